// Round 9
// baseline (592.506 us; speedup 1.0000x reference)
//
#include <hip/hip_runtime.h>

typedef unsigned short u16;
typedef __bf16 bf16_t;
typedef bf16_t bf16x8 __attribute__((ext_vector_type(8)));
typedef bf16_t bf16x4 __attribute__((ext_vector_type(4)));
typedef float f32x4 __attribute__((ext_vector_type(4)));

__device__ __forceinline__ u16 f2b(float f){
  unsigned u = __builtin_bit_cast(unsigned, f);
  u += 0x7fffu + ((u >> 16) & 1u);
  return (u16)(u >> 16);
}
__device__ __forceinline__ float b2f(u16 h){
  return __builtin_bit_cast(float, ((unsigned)h) << 16);
}
__device__ __forceinline__ float gelu_exact(float x){
  return 0.5f * x * (1.f + erff(x * 0.70710678118654752440f));
}
__device__ __forceinline__ void gld16(const void* g, void* l){
  __builtin_amdgcn_global_load_lds((const __attribute__((address_space(1))) unsigned int*)g,
                                   (__attribute__((address_space(3))) unsigned int*)l, 16, 0, 0);
}

// ---------------------------------------------------------------- prep kernels
struct ConvArgs { const float* s[8]; u16* d[8]; unsigned cum[8]; };

// one kernel converts all 8 weight matrices f32->bf16 (4 elems/thread)
__global__ __launch_bounds__(256) void k_convall(ConvArgs a){
  unsigned g = blockIdx.x * 256 + threadIdx.x;     // 4-elem group id
  int seg = 0;
#pragma unroll
  for (int i = 0; i < 7; ++i) seg += (g >= a.cum[i]);
  unsigned base = seg ? a.cum[seg - 1] : 0u;
  unsigned idx = (g - base) * 4;
  float4 v = *(const float4*)(a.s[seg] + idx);
  ushort4 o; o.x = f2b(v.x); o.y = f2b(v.y); o.z = f2b(v.z); o.w = f2b(v.w);
  *(ushort4*)(a.d[seg] + idx) = o;
}

__global__ void k_w5(const float* __restrict__ W5, const float* __restrict__ b5,
                     const float* __restrict__ ew, u16* __restrict__ Wc,
                     float* __restrict__ b5c, float* __restrict__ outW){
  int gid = blockIdx.x * 256 + threadIdx.x;           // covers 1048576
  float e0 = ew[0], e1 = ew[1], e2 = ew[2], e3 = ew[3], e4 = ew[4];
  float mx = fmaxf(fmaxf(fmaxf(e0, e1), fmaxf(e2, e3)), e4);
  float x0 = __expf(e0 - mx), x1 = __expf(e1 - mx), x2 = __expf(e2 - mx), x3 = __expf(e3 - mx), x4 = __expf(e4 - mx);
  float inv = 1.f / (x0 + x1 + x2 + x3 + x4);
  float w0 = x0 * inv, w1 = x1 * inv, w2 = x2 * inv, w3 = x3 * inv, w4 = x4 * inv;
  float v = w0 * W5[gid] + w1 * W5[gid + 1048576] + w2 * W5[gid + 2097152]
          + w3 * W5[gid + 3145728] + w4 * W5[gid + 4194304];
  Wc[gid] = f2b(v);
  if (gid < 1024)
    b5c[gid] = w0 * b5[gid] + w1 * b5[gid + 1024] + w2 * b5[gid + 2048]
             + w3 * b5[gid + 3072] + w4 * b5[gid + 4096];
  if (gid == 0){ outW[0] = w0; outW[1] = w1; outW[2] = w2; outW[3] = w3; outW[4] = w4; }
}

__global__ void k_fused(const float* __restrict__ pos, const float* __restrict__ tim,
                        u16* __restrict__ d){
  int i = blockIdx.x * 256 + threadIdx.x;             // 1048576
  int t = i >> 10, c = i & 1023;
  float v = (c < 512) ? pos[t * 512 + c] : tim[t * 512 + c - 512];
  d[i] = f2b(v);
}

__global__ void k_bqkv(const float* __restrict__ bq, const float* __restrict__ bk,
                       const float* __restrict__ bv, float* __restrict__ d){
  int i = blockIdx.x * 256 + threadIdx.x;
  if (i >= 3072) return;
  d[i] = (i < 1024) ? bq[i] : (i < 2048 ? bk[i - 1024] : bv[i - 2048]);
}

__global__ void k_xinit(const float* __restrict__ xin, const float* __restrict__ tmp,
                        float* __restrict__ x){
  int i = blockIdx.x * 256 + threadIdx.x;
  float4 a = ((const float4*)xin)[i];
  float4 b = ((const float4*)tmp)[i & 262143];
  float4 o; o.x = a.x + b.x; o.y = a.y + b.y; o.z = a.z + b.z; o.w = a.w + b.w;
  ((float4*)x)[i] = o;
}

__global__ __launch_bounds__(256) void k_ln(const float* __restrict__ x, const float* __restrict__ g,
                     const float* __restrict__ be, u16* __restrict__ out){
  int row = blockIdx.x, tid = threadIdx.x;
  int w = tid >> 6, lane = tid & 63;
  const float4 v = ((const float4*)(x + (size_t)row * 1024))[tid];
  float s1 = v.x + v.y + v.z + v.w;
  float s2 = v.x * v.x + v.y * v.y + v.z * v.z + v.w * v.w;
  for (int m = 1; m < 64; m <<= 1){ s1 += __shfl_xor(s1, m, 64); s2 += __shfl_xor(s2, m, 64); }
  __shared__ float a1[4], a2[4];
  if (!lane){ a1[w] = s1; a2[w] = s2; }
  __syncthreads();
  s1 = a1[0] + a1[1] + a1[2] + a1[3];
  s2 = a2[0] + a2[1] + a2[2] + a2[3];
  float mean = s1 * (1.f / 1024.f);
  float var  = s2 * (1.f / 1024.f) - mean * mean;
  float rstd = rsqrtf(var + 1e-5f);
  float4 gv = ((const float4*)g)[tid], bv = ((const float4*)be)[tid];
  ushort4 o;
  o.x = f2b((v.x - mean) * rstd * gv.x + bv.x);
  o.y = f2b((v.y - mean) * rstd * gv.y + bv.y);
  o.z = f2b((v.z - mean) * rstd * gv.z + bv.z);
  o.w = f2b((v.w - mean) * rstd * gv.w + bv.w);
  ((ushort4*)(out + (size_t)row * 1024))[tid] = o;
}

__global__ __launch_bounds__(256) void k_mech(const u16* __restrict__ m1, const float* __restrict__ Wm2,
                      const float* __restrict__ bm2, float* __restrict__ outMech,
                      float* __restrict__ mechf){
  int tid = threadIdx.x, w = tid >> 6, lane = tid & 63;
  int r = blockIdx.x * 4 + w;
  uint4 mv = *(const uint4*)(m1 + (size_t)r * 512 + lane * 8);
  const u16* ms = (const u16*)&mv;
  float4 w0 = ((const float4*)Wm2)[lane * 2];
  float4 w1 = ((const float4*)Wm2)[lane * 2 + 1];
  float dot = b2f(ms[0]) * w0.x + b2f(ms[1]) * w0.y + b2f(ms[2]) * w0.z + b2f(ms[3]) * w0.w
            + b2f(ms[4]) * w1.x + b2f(ms[5]) * w1.y + b2f(ms[6]) * w1.z + b2f(ms[7]) * w1.w;
  for (int m = 1; m < 64; m <<= 1) dot += __shfl_xor(dot, m, 64);
  if (lane == 0){
    float z = dot + bm2[0];
    float sig = 1.f / (1.f + __expf(-z));
    outMech[r] = sig;
    mechf[r] = (1.f + sig) * 0.125f;   // folded (1+mech)/sqrt(dh)
  }
}

// V transpose: qkv v-part [token][d] -> vT[(b*16+h)*64+d][token]
__global__ __launch_bounds__(256) void k_vt(const u16* __restrict__ qkv, u16* __restrict__ vT){
  __shared__ u16 lt[64 * 64];
  const int tid = threadIdx.x;
  const int b = blockIdx.z, h = blockIdx.y, t0 = blockIdx.x * 64;
  const size_t base = (size_t)b * 1024;
#pragma unroll
  for (int i = 0; i < 2; ++i){
    int c = i * 256 + tid;
    int r = c >> 3, ch = c & 7;
    uint4 v = *(const uint4*)(qkv + (base + t0 + r) * 3072 + 2048 + h * 64 + ch * 8);
    *(uint4*)((char*)lt + r * 128 + ((ch ^ (r & 7)) << 4)) = v;
  }
  __syncthreads();
  int d = tid >> 2, tt = (tid & 3) * 16;
  u16 o[16];
#pragma unroll
  for (int j = 0; j < 16; ++j){
    int t = tt + j;
    o[j] = *(const u16*)((char*)lt + t * 128 + (((d >> 3) ^ (t & 7)) << 4) + (d & 7) * 2);
  }
  u16* dst = vT + ((size_t)(b * 16 + h) * 64 + d) * 1024 + t0 + tt;
  *(uint4*)dst = *(uint4*)&o[0];
  *(uint4*)(dst + 8) = *(uint4*)&o[8];
}

// ---------------------------------------------------------------- GEMM
// out[m][n] = act(A[m][:] . W[n][:] + bias[n]) (+resid)
// Depth-2 pipelined staging: 3 LDS buffers, counted vmcnt (never 0 in loop),
// raw s_barrier. BM = 128 or 256 (n-tile fixed 128).
// Block mapping: bijective XCD swizzle -> supertile strips of 8 n-blocks,
// m-major within strip => per-XCD L2 working set ~= A-rows + 8 W-cols (<~4MB).
template<bool GELU_, bool RES, bool OUTF_EN, bool OUTB_EN, bool PARTIAL, int BM>
__global__ __launch_bounds__(256) void k_gemm(const u16* __restrict__ A, const u16* __restrict__ W,
                      const float* __restrict__ bias, const float* resid,
                      float* outF, u16* outB, u16* pOut, int M, int N, int K, int nbx){
  constexpr int MB = BM / 32;              // m-fragments per wave
  constexpr int ACH = BM * 4;              // A chunks (16B) per tile
  constexpr int AIT = ACH / 256;           // A stage iterations
  __shared__ u16 lA[3][BM * 32];
  __shared__ u16 lB[3][128 * 32];
  const int tid = threadIdx.x;
  const int w = tid >> 6, lane = tid & 63;
  const int lr = lane & 15, lg = lane >> 4;
  // bijective XCD swizzle (m204): each XCD gets a contiguous swz range
  const int nwg = gridDim.x;
  const int q = nwg >> 3, r = nwg & 7;
  const int xcd = blockIdx.x & 7, loc = blockIdx.x >> 3;
  const int swz = (xcd < r ? xcd * (q + 1) : r * (q + 1) + (xcd - r) * q) + loc;
  // supertile: strips of SW n-blocks, m-major within strip
  const int nby = nwg / nbx;
  const int SW = (nbx & 7) ? nbx : 8;
  const int ss = nby * SW;
  const int strip = swz / ss, rem = swz % ss;
  const int m0 = (rem / SW) * BM;
  const int n0 = (strip * SW + rem % SW) * 128;
  const int wr = (w >> 1) * (BM / 2), wc = (w & 1) * 64;
  const int kb = blockIdx.z;
  const int Ks = K / gridDim.z;
  const int kbeg = kb * Ks;
  const int nsteps = Ks >> 5;

  f32x4 acc[MB][4] = {};
  const char* gA = (const char*)A;
  const char* gW = (const char*)W;

  auto stage = [&](int buf, int k0){
#pragma unroll
    for (int i = 0; i < AIT; ++i){
      int c = i * 256 + tid;                 // 16B chunk id of A tile (4 chunks/row)
      gld16(gA + (((size_t)(m0 + (c >> 2)) * K + k0) * 2 + (c & 3) * 16),
            (char*)lA + buf * (BM * 64) + i * 4096 + w * 1024);
    }
#pragma unroll
    for (int i = 0; i < 2; ++i){
      int c = i * 256 + tid;
      gld16(gW + (((size_t)(n0 + (c >> 2)) * K + k0) * 2 + (c & 3) * 16),
            (char*)lB + buf * 8192 + i * 4096 + w * 1024);
    }
  };

  // prologue: stage 2 tiles ahead
  stage(0, kbeg);
  if (nsteps > 1) stage(1, kbeg + 32);
  int cur = 0, nx = 1, pf = 2;
  for (int s = 0; s < nsteps; ++s){
    if (s + 2 < nsteps) stage(pf, kbeg + (s + 2) * 32);
    // wait ONLY the oldest stage's loads; rest stay in flight across the barrier
    if (s + 2 < nsteps){
      if (BM == 256) asm volatile("s_waitcnt vmcnt(12)" ::: "memory");
      else           asm volatile("s_waitcnt vmcnt(8)"  ::: "memory");
    } else if (s + 1 < nsteps){
      if (BM == 256) asm volatile("s_waitcnt vmcnt(6)" ::: "memory");
      else           asm volatile("s_waitcnt vmcnt(4)" ::: "memory");
    } else {
      asm volatile("s_waitcnt vmcnt(0)" ::: "memory");
    }
    __builtin_amdgcn_s_barrier();            // tile cur fully in LDS for all waves
    bf16x8 af[MB], wf[4];
#pragma unroll
    for (int mb = 0; mb < MB; ++mb)
      af[mb] = *reinterpret_cast<const bf16x8*>(&lA[cur][(wr + mb * 16 + lr) * 32 + lg * 8]);
#pragma unroll
    for (int nb = 0; nb < 4; ++nb)
      wf[nb] = *reinterpret_cast<const bf16x8*>(&lB[cur][(wc + nb * 16 + lr) * 32 + lg * 8]);
#pragma unroll
    for (int mb = 0; mb < MB; ++mb)
#pragma unroll
      for (int nb = 0; nb < 4; ++nb)
        acc[mb][nb] = __builtin_amdgcn_mfma_f32_16x16x32_bf16(af[mb], wf[nb], acc[mb][nb], 0, 0, 0);
    __builtin_amdgcn_s_barrier();            // all waves done reading cur
    int t = cur; cur = nx; nx = pf; pf = t;
  }

#pragma unroll
  for (int mb = 0; mb < MB; ++mb){
#pragma unroll
    for (int nb = 0; nb < 4; ++nb){
      int col = n0 + wc + nb * 16 + lr;
      float bv = PARTIAL ? 0.f : bias[col];
#pragma unroll
      for (int ii = 0; ii < 4; ++ii){
        int row = m0 + wr + mb * 16 + lg * 4 + ii;
        float v = acc[mb][nb][ii] + bv;
        if (GELU_) v = gelu_exact(v);
        size_t idx = (size_t)row * N + col;
        if (RES) v += resid[idx];
        if (PARTIAL) pOut[(size_t)kb * M * N + idx] = f2b(v);
        if (OUTF_EN) outF[idx] = v;
        if (OUTB_EN) outB[idx] = f2b(v);
      }
    }
  }
}

// reduce 2 bf16 K-split partials + bias + resid -> float out
__global__ __launch_bounds__(256) void k_red(const u16* __restrict__ pw, const float* __restrict__ bias,
                     const float* __restrict__ resid, float* __restrict__ outF, int MN, int N){
  int i = (blockIdx.x * 256 + threadIdx.x) * 8;
  uint4 v0 = *(const uint4*)(pw + i);
  uint4 v1 = *(const uint4*)(pw + MN + i);
  const u16* a = (const u16*)&v0;
  const u16* b = (const u16*)&v1;
  int col = i & (N - 1);
  float4 bv0 = *(const float4*)(bias + col);
  float4 bv1 = *(const float4*)(bias + col + 4);
  float4 r0 = *(const float4*)(resid + i);
  float4 r1 = *(const float4*)(resid + i + 4);
  float4 o0, o1;
  o0.x = b2f(a[0]) + b2f(b[0]) + bv0.x + r0.x;
  o0.y = b2f(a[1]) + b2f(b[1]) + bv0.y + r0.y;
  o0.z = b2f(a[2]) + b2f(b[2]) + bv0.z + r0.z;
  o0.w = b2f(a[3]) + b2f(b[3]) + bv0.w + r0.w;
  o1.x = b2f(a[4]) + b2f(b[4]) + bv1.x + r1.x;
  o1.y = b2f(a[5]) + b2f(b[5]) + bv1.y + r1.y;
  o1.z = b2f(a[6]) + b2f(b[6]) + bv1.z + r1.z;
  o1.w = b2f(a[7]) + b2f(b[7]) + bv1.w + r1.w;
  *(float4*)(outF + i) = o0;
  *(float4*)(outF + i + 4) = o1;
}

// ---------------------------------------------------------------- flash attention
// qkv: [B*T][3072] bf16 (q|k|.), vT: [(b*16+h)*64+d][1024] bf16, mechf: (1+mech)/8
__global__ __launch_bounds__(256) void k_attn(const u16* __restrict__ qkv, const u16* __restrict__ vT,
                      const float* __restrict__ mechf, u16* __restrict__ ctx){
  __shared__ u16 lk[64 * 64];        // K tile [key][d], XOR-swizzled chunks
  __shared__ u16 lvt[64 * 64];       // V^T tile [d][key], XOR-swizzled chunks
  __shared__ u16 lpt[4][64 * 16];    // per-wave P^T tile [key][q]
  __shared__ float lmf[64];
  const int tid = threadIdx.x, w = tid >> 6, lane = tid & 63;
  const int lr = lane & 15, lg = lane >> 4;
  const int b = blockIdx.z, h = blockIdx.y, q0 = blockIdx.x * 64;
  const size_t base = (size_t)b * 1024;
  const size_t bh = (size_t)(b * 16 + h);

  bf16x8 qf[2];
  {
    const u16* qrow = qkv + (base + q0 + w * 16 + lr) * 3072 + h * 64;
    qf[0] = *(const bf16x8*)(qrow + lg * 8);
    qf[1] = *(const bf16x8*)(qrow + 32 + lg * 8);
  }
  float m_i[4], l_i[4];
  f32x4 cacc[4] = {};
#pragma unroll
  for (int i = 0; i < 4; ++i){ m_i[i] = -1e30f; l_i[i] = 0.f; }

  char* lkb = (char*)lk;
  char* lvb = (char*)lvt;
  unsigned lpw = (unsigned)(uintptr_t)(__attribute__((address_space(3))) u16*)&lpt[w][0];
  unsigned ta = lpw + lg * 256 + lr * 8;

  for (int jt = 0; jt < 1024; jt += 64){
    __syncthreads();
#pragma unroll
    for (int i = 0; i < 2; ++i){
      int c = i * 256 + tid;                  // 512 chunks of 16B per tile
      int row = c >> 3, ch = c & 7;
      int chs = ch ^ (row & 7);               // pre-swizzled global source
      gld16(qkv + (base + jt + row) * 3072 + 1024 + h * 64 + chs * 8,
            lkb + i * 4096 + w * 1024);
      gld16(vT + (bh * 64 + row) * 1024 + jt + chs * 8,
            lvb + i * 4096 + w * 1024);
    }
    if (tid < 64) lmf[tid] = mechf[base + jt + tid];
    __syncthreads();

    // ---- QK^T (8 MFMA/wave)
    f32x4 s[4];
    __builtin_amdgcn_s_setprio(1);
#pragma unroll
    for (int kb = 0; kb < 4; ++kb){
      int row = kb * 16 + lr;
      bf16x8 kf0 = *(const bf16x8*)(lkb + row * 128 + ((lg ^ (row & 7)) << 4));
      bf16x8 kf1 = *(const bf16x8*)(lkb + row * 128 + (((4 + lg) ^ (row & 7)) << 4));
      f32x4 z = {};
      z = __builtin_amdgcn_mfma_f32_16x16x32_bf16(qf[0], kf0, z, 0, 0, 0);
      z = __builtin_amdgcn_mfma_f32_16x16x32_bf16(qf[1], kf1, z, 0, 0, 0);
      float f = lmf[row];
      s[kb] = z * f;
    }
    __builtin_amdgcn_s_setprio(0);

    // ---- online softmax
    float tm[4];
#pragma unroll
    for (int i = 0; i < 4; ++i)
      tm[i] = fmaxf(fmaxf(s[0][i], s[1][i]), fmaxf(s[2][i], s[3][i]));
#pragma unroll
    for (int off = 1; off < 16; off <<= 1)
#pragma unroll
      for (int i = 0; i < 4; ++i) tm[i] = fmaxf(tm[i], __shfl_xor(tm[i], off, 64));
    float sc[4];
#pragma unroll
    for (int i = 0; i < 4; ++i){
      float mn = fmaxf(m_i[i], tm[i]);
      sc[i] = __expf(m_i[i] - mn);
      m_i[i] = mn;
    }
    // P = exp(s - m); write P^T [key][q] as one b64 per (lane,kb)
#pragma unroll
    for (int kb = 0; kb < 4; ++kb){
      ushort4 pk;
      float p0 = __expf(s[kb][0] - m_i[0]); s[kb][0] = p0; pk.x = f2b(p0);
      float p1 = __expf(s[kb][1] - m_i[1]); s[kb][1] = p1; pk.y = f2b(p1);
      float p2 = __expf(s[kb][2] - m_i[2]); s[kb][2] = p2; pk.z = f2b(p2);
      float p3 = __expf(s[kb][3] - m_i[3]); s[kb][3] = p3; pk.w = f2b(p3);
      *(uint2*)((char*)&lpt[w][0] + (kb * 16 + lr) * 32 + lg * 8) =
          __builtin_bit_cast(uint2, pk);
    }
#pragma unroll
    for (int i = 0; i < 4; ++i){
      float r = (s[0][i] + s[1][i]) + (s[2][i] + s[3][i]);
#pragma unroll
      for (int off = 1; off < 16; off <<= 1) r += __shfl_xor(r, off, 64);
      l_i[i] = l_i[i] * sc[i] + r;
#pragma unroll
      for (int db = 0; db < 4; ++db) cacc[db][i] *= sc[i];
    }

    // ---- P^T -> A-fragments via hardware transpose read
    asm volatile("s_waitcnt lgkmcnt(0)" ::: "memory");
    bf16x4 t00, t01, t10, t11;
    asm volatile("ds_read_b64_tr_b16 %0, %1 offset:0"    : "=v"(t00) : "v"(ta));
    asm volatile("ds_read_b64_tr_b16 %0, %1 offset:128"  : "=v"(t01) : "v"(ta));
    asm volatile("ds_read_b64_tr_b16 %0, %1 offset:1024" : "=v"(t10) : "v"(ta));
    asm volatile("ds_read_b64_tr_b16 %0, %1 offset:1152" : "=v"(t11) : "v"(ta));
    asm volatile("s_waitcnt lgkmcnt(0)");
    __builtin_amdgcn_sched_barrier(0);
    bf16x8 pf0 = __builtin_shufflevector(t00, t01, 0, 1, 2, 3, 4, 5, 6, 7);
    bf16x8 pf1 = __builtin_shufflevector(t10, t11, 0, 1, 2, 3, 4, 5, 6, 7);

    // ---- PV (8 MFMA/wave)
    __builtin_amdgcn_s_setprio(1);
#pragma unroll
    for (int db = 0; db < 4; ++db){
      int row = db * 16 + lr;
      bf16x8 vf0 = *(const bf16x8*)(lvb + row * 128 + ((lg ^ (row & 7)) << 4));
      bf16x8 vf1 = *(const bf16x8*)(lvb + row * 128 + (((4 + lg) ^ (row & 7)) << 4));
      cacc[db] = __builtin_amdgcn_mfma_f32_16x16x32_bf16(pf0, vf0, cacc[db], 0, 0, 0);
      cacc[db] = __builtin_amdgcn_mfma_f32_16x16x32_bf16(pf1, vf1, cacc[db], 0, 0, 0);
    }
    __builtin_amdgcn_s_setprio(0);
  }
  size_t orow0 = base + q0 + w * 16;
#pragma unroll
  for (int db = 0; db < 4; ++db)
#pragma unroll
    for (int i = 0; i < 4; ++i)
      ctx[(orow0 + lg * 4 + i) * 1024 + h * 64 + db * 16 + lr] = f2b(cacc[db][i] / l_i[i]);
}

// ---------------------------------------------------------------- host
extern "C" void kernel_launch(void* const* d_in, const int* in_sizes, int n_in,
                              void* d_out, int out_size, void* d_ws, size_t ws_size,
                              hipStream_t stream){
  const float* x_in = (const float*)d_in[0];
  const float* pos  = (const float*)d_in[1];
  const float* tim  = (const float*)d_in[2];
  const float* Wint = (const float*)d_in[3];
  const float* bint = (const float*)d_in[4];
  const float* g1   = (const float*)d_in[5];
  const float* be1  = (const float*)d_in[6];
  const float* Wq   = (const float*)d_in[7];
  const float* bq   = (const float*)d_in[8];
  const float* Wk   = (const float*)d_in[9];
  const float* bk   = (const float*)d_in[10];
  const float* Wv   = (const float*)d_in[11];
  const float* bv   = (const float*)d_in[12];
  const float* Wo   = (const float*)d_in[13];
  const float* bo   = (const float*)d_in[14];
  const float* Wm1  = (const float*)d_in[15];
  const float* bm1  = (const float*)d_in[16];
  const float* Wm2  = (const float*)d_in[17];
  const float* bm2  = (const float*)d_in[18];
  const float* g2   = (const float*)d_in[19];
  const float* be2  = (const float*)d_in[20];
  const float* W5   = (const float*)d_in[21];
  const float* b5   = (const float*)d_in[22];
  const float* ew   = (const float*)d_in[23];
  const float* g3   = (const float*)d_in[24];
  const float* be3  = (const float*)d_in[25];
  const float* Wf1  = (const float*)d_in[26];
  const float* bf1  = (const float*)d_in[27];
  const float* Wf2  = (const float*)d_in[28];
  const float* bf2  = (const float*)d_in[29];

  float* outX = (float*)d_out;
  float* outM = outX + 4194304;
  float* outW = outX + 4198400;

  char* p = (char*)d_ws;
  auto alloc = [&](size_t bytes) -> char* {
    char* r = p; p += (bytes + 255) & ~(size_t)255; return r;
  };
  u16* Wint_b = (u16*)alloc(1048576 * 2);
  u16* Wqkv_b = (u16*)alloc(3145728 * 2);
  u16* Wm1_b  = (u16*)alloc(524288 * 2);
  u16* Wo_b   = (u16*)alloc(1048576 * 2);
  u16* Wc_b   = (u16*)alloc(1048576 * 2);
  u16* Wf1_b  = (u16*)alloc(4194304 * 2);
  u16* Wf2_b  = (u16*)alloc(4194304 * 2);
  u16* fus_b  = (u16*)alloc(1048576 * 2);
  float* bqkv = (float*)alloc(3072 * 4);
  float* b5c  = (float*)alloc(1024 * 4);
  float* mechf= (float*)alloc(4096 * 4);
  float* tmpF = (float*)alloc(1048576 * 4);
  float* xbuf = (float*)alloc(4194304 * 4);
  u16* h_b    = (u16*)alloc(4194304 * 2);
  char* big   = alloc(36 * 1024 * 1024);        // overlapped region
  u16* qkv_b  = (u16*)big;                      // [4096][3072] bf16 (24MB)
  u16* m1_b   = (u16*)(big + 24 * 1024 * 1024); // [4096][512]  bf16 (4MB)
  u16* ctx_b  = (u16*)(big + 28 * 1024 * 1024); // [4096][1024] bf16 (8MB)
  u16* f1_b   = (u16*)big;                      // [4096][4096] bf16 (32MB) after attn
  u16* vT_b   = h_b;                            // reuse h_b (free after k_mech, until norm2)
  u16* pw_b   = (u16*)d_ws;                     // 16MB FFN2 partials: overlaps Wint..Wf1 (dead by FFN2)

  dim3 blk(256);
  // weight prep: single fused conversion kernel (8 matrices, 13.5M elems)
  ConvArgs ca;
  ca.s[0] = Wint; ca.d[0] = Wint_b;
  ca.s[1] = Wq;   ca.d[1] = Wqkv_b;
  ca.s[2] = Wk;   ca.d[2] = Wqkv_b + 1048576;
  ca.s[3] = Wv;   ca.d[3] = Wqkv_b + 2097152;
  ca.s[4] = Wm1;  ca.d[4] = Wm1_b;
  ca.s[5] = Wo;   ca.d[5] = Wo_b;
  ca.s[6] = Wf1;  ca.d[6] = Wf1_b;
  ca.s[7] = Wf2;  ca.d[7] = Wf2_b;
  ca.cum[0] = 262144;  ca.cum[1] = 524288;  ca.cum[2] = 786432;  ca.cum[3] = 1048576;
  ca.cum[4] = 1179648; ca.cum[5] = 1441792; ca.cum[6] = 2490368; ca.cum[7] = 3538944;
  k_convall<<<13824, blk, 0, stream>>>(ca);
  k_w5<<<4096, blk, 0, stream>>>(W5, b5, ew, Wc_b, b5c, outW);
  k_fused<<<4096, blk, 0, stream>>>(pos, tim, fus_b);
  k_bqkv<<<12, blk, 0, stream>>>(bq, bk, bv, bqkv);

  // fused pos/time GEMM -> tmp, then x = x_in + tmp
  k_gemm<false,false,true,false,false,128><<<dim3(64, 1, 1), blk, 0, stream>>>(
      fus_b, Wint_b, bint, nullptr, tmpF, nullptr, nullptr, 1024, 1024, 1024, 8);
  k_xinit<<<4096, blk, 0, stream>>>(x_in, tmpF, xbuf);

  // attention block
  k_ln<<<4096, blk, 0, stream>>>(xbuf, g1, be1, h_b);
  k_gemm<false,false,false,true,false,128><<<dim3(768, 1, 1), blk, 0, stream>>>(
      h_b, Wqkv_b, bqkv, nullptr, nullptr, qkv_b, nullptr, 4096, 3072, 1024, 24);
  k_gemm<true,false,false,true,false,128><<<dim3(128, 1, 1), blk, 0, stream>>>(
      h_b, Wm1_b, bm1, nullptr, nullptr, m1_b, nullptr, 4096, 512, 1024, 4);
  k_mech<<<1024, blk, 0, stream>>>(m1_b, Wm2, bm2, outM, mechf);
  k_vt<<<dim3(16, 16, 4), blk, 0, stream>>>(qkv_b, vT_b);
  k_attn<<<dim3(16, 16, 4), blk, 0, stream>>>(qkv_b, vT_b, mechf, ctx_b);
  k_gemm<false,true,true,false,false,128><<<dim3(256, 1, 1), blk, 0, stream>>>(
      ctx_b, Wo_b, bo, xbuf, xbuf, nullptr, nullptr, 4096, 1024, 1024, 8);

  // five-elements layer (W5 pre-reduced)
  k_ln<<<4096, blk, 0, stream>>>(xbuf, g2, be2, h_b);
  k_gemm<false,true,true,false,false,128><<<dim3(256, 1, 1), blk, 0, stream>>>(
      h_b, Wc_b, b5c, xbuf, xbuf, nullptr, nullptr, 4096, 1024, 1024, 8);

  // FFN
  k_ln<<<4096, blk, 0, stream>>>(xbuf, g3, be3, h_b);
  // FFN1: BM=256 tile (grid 512 = 2 blocks/CU), GELU, bf16 out
  k_gemm<true,false,false,true,false,256><<<dim3(512, 1, 1), blk, 0, stream>>>(
      h_b, Wf1_b, bf1, nullptr, nullptr, f1_b, nullptr, 4096, 4096, 1024, 32);
  // FFN2: split-K x2, bf16 partials, then fused reduce(+bias+resid)->outX
  k_gemm<false,false,false,false,true,128><<<dim3(256, 1, 2), blk, 0, stream>>>(
      f1_b, Wf2_b, nullptr, nullptr, nullptr, nullptr, pw_b, 4096, 1024, 4096, 8);
  k_red<<<2048, blk, 0, stream>>>(pw_b, bf2, xbuf, outX, 4194304, 1024);
}

// Round 10
// 550.997 us; speedup vs baseline: 1.0753x; 1.0753x over previous
//
#include <hip/hip_runtime.h>

typedef unsigned short u16;
typedef __bf16 bf16_t;
typedef bf16_t bf16x8 __attribute__((ext_vector_type(8)));
typedef bf16_t bf16x4 __attribute__((ext_vector_type(4)));
typedef float f32x4 __attribute__((ext_vector_type(4)));

__device__ __forceinline__ u16 f2b(float f){
  unsigned u = __builtin_bit_cast(unsigned, f);
  u += 0x7fffu + ((u >> 16) & 1u);
  return (u16)(u >> 16);
}
__device__ __forceinline__ float b2f(u16 h){
  return __builtin_bit_cast(float, ((unsigned)h) << 16);
}
__device__ __forceinline__ float gelu_exact(float x){
  return 0.5f * x * (1.f + erff(x * 0.70710678118654752440f));
}
__device__ __forceinline__ void gld16(const void* g, void* l){
  __builtin_amdgcn_global_load_lds((const __attribute__((address_space(1))) unsigned int*)g,
                                   (__attribute__((address_space(3))) unsigned int*)l, 16, 0, 0);
}

// ---------------------------------------------------------------- prep kernels
struct ConvArgs { const float* s[8]; u16* d[8]; unsigned cum[8]; };

// one kernel converts all 8 weight matrices f32->bf16 (4 elems/thread)
__global__ __launch_bounds__(256) void k_convall(ConvArgs a){
  unsigned g = blockIdx.x * 256 + threadIdx.x;     // 4-elem group id
  int seg = 0;
#pragma unroll
  for (int i = 0; i < 7; ++i) seg += (g >= a.cum[i]);
  unsigned base = seg ? a.cum[seg - 1] : 0u;
  unsigned idx = (g - base) * 4;
  float4 v = *(const float4*)(a.s[seg] + idx);
  ushort4 o; o.x = f2b(v.x); o.y = f2b(v.y); o.z = f2b(v.z); o.w = f2b(v.w);
  *(ushort4*)(a.d[seg] + idx) = o;
}

__global__ void k_w5(const float* __restrict__ W5, const float* __restrict__ b5,
                     const float* __restrict__ ew, u16* __restrict__ Wc,
                     float* __restrict__ b5c, float* __restrict__ outW){
  int gid = blockIdx.x * 256 + threadIdx.x;           // covers 1048576
  float e0 = ew[0], e1 = ew[1], e2 = ew[2], e3 = ew[3], e4 = ew[4];
  float mx = fmaxf(fmaxf(fmaxf(e0, e1), fmaxf(e2, e3)), e4);
  float x0 = __expf(e0 - mx), x1 = __expf(e1 - mx), x2 = __expf(e2 - mx), x3 = __expf(e3 - mx), x4 = __expf(e4 - mx);
  float inv = 1.f / (x0 + x1 + x2 + x3 + x4);
  float w0 = x0 * inv, w1 = x1 * inv, w2 = x2 * inv, w3 = x3 * inv, w4 = x4 * inv;
  float v = w0 * W5[gid] + w1 * W5[gid + 1048576] + w2 * W5[gid + 2097152]
          + w3 * W5[gid + 3145728] + w4 * W5[gid + 4194304];
  Wc[gid] = f2b(v);
  if (gid < 1024)
    b5c[gid] = w0 * b5[gid] + w1 * b5[gid + 1024] + w2 * b5[gid + 2048]
             + w3 * b5[gid + 3072] + w4 * b5[gid + 4096];
  if (gid == 0){ outW[0] = w0; outW[1] = w1; outW[2] = w2; outW[3] = w3; outW[4] = w4; }
}

__global__ void k_fused(const float* __restrict__ pos, const float* __restrict__ tim,
                        u16* __restrict__ d){
  int i = blockIdx.x * 256 + threadIdx.x;             // 1048576
  int t = i >> 10, c = i & 1023;
  float v = (c < 512) ? pos[t * 512 + c] : tim[t * 512 + c - 512];
  d[i] = f2b(v);
}

__global__ void k_bqkv(const float* __restrict__ bq, const float* __restrict__ bk,
                       const float* __restrict__ bv, float* __restrict__ d){
  int i = blockIdx.x * 256 + threadIdx.x;
  if (i >= 3072) return;
  d[i] = (i < 1024) ? bq[i] : (i < 2048 ? bk[i - 1024] : bv[i - 2048]);
}

__global__ void k_xinit(const float* __restrict__ xin, const float* __restrict__ tmp,
                        float* __restrict__ x){
  int i = blockIdx.x * 256 + threadIdx.x;
  float4 a = ((const float4*)xin)[i];
  float4 b = ((const float4*)tmp)[i & 262143];
  float4 o; o.x = a.x + b.x; o.y = a.y + b.y; o.z = a.z + b.z; o.w = a.w + b.w;
  ((float4*)x)[i] = o;
}

__global__ __launch_bounds__(256) void k_ln(const float* __restrict__ x, const float* __restrict__ g,
                     const float* __restrict__ be, u16* __restrict__ out){
  int row = blockIdx.x, tid = threadIdx.x;
  int w = tid >> 6, lane = tid & 63;
  const float4 v = ((const float4*)(x + (size_t)row * 1024))[tid];
  float s1 = v.x + v.y + v.z + v.w;
  float s2 = v.x * v.x + v.y * v.y + v.z * v.z + v.w * v.w;
  for (int m = 1; m < 64; m <<= 1){ s1 += __shfl_xor(s1, m, 64); s2 += __shfl_xor(s2, m, 64); }
  __shared__ float a1[4], a2[4];
  if (!lane){ a1[w] = s1; a2[w] = s2; }
  __syncthreads();
  s1 = a1[0] + a1[1] + a1[2] + a1[3];
  s2 = a2[0] + a2[1] + a2[2] + a2[3];
  float mean = s1 * (1.f / 1024.f);
  float var  = s2 * (1.f / 1024.f) - mean * mean;
  float rstd = rsqrtf(var + 1e-5f);
  float4 gv = ((const float4*)g)[tid], bv = ((const float4*)be)[tid];
  ushort4 o;
  o.x = f2b((v.x - mean) * rstd * gv.x + bv.x);
  o.y = f2b((v.y - mean) * rstd * gv.y + bv.y);
  o.z = f2b((v.z - mean) * rstd * gv.z + bv.z);
  o.w = f2b((v.w - mean) * rstd * gv.w + bv.w);
  ((ushort4*)(out + (size_t)row * 1024))[tid] = o;
}

__global__ __launch_bounds__(256) void k_mech(const u16* __restrict__ m1, const float* __restrict__ Wm2,
                      const float* __restrict__ bm2, float* __restrict__ outMech,
                      float* __restrict__ mechf){
  int tid = threadIdx.x, w = tid >> 6, lane = tid & 63;
  int r = blockIdx.x * 4 + w;
  uint4 mv = *(const uint4*)(m1 + (size_t)r * 512 + lane * 8);
  const u16* ms = (const u16*)&mv;
  float4 w0 = ((const float4*)Wm2)[lane * 2];
  float4 w1 = ((const float4*)Wm2)[lane * 2 + 1];
  float dot = b2f(ms[0]) * w0.x + b2f(ms[1]) * w0.y + b2f(ms[2]) * w0.z + b2f(ms[3]) * w0.w
            + b2f(ms[4]) * w1.x + b2f(ms[5]) * w1.y + b2f(ms[6]) * w1.z + b2f(ms[7]) * w1.w;
  for (int m = 1; m < 64; m <<= 1) dot += __shfl_xor(dot, m, 64);
  if (lane == 0){
    float z = dot + bm2[0];
    float sig = 1.f / (1.f + __expf(-z));
    outMech[r] = sig;
    mechf[r] = (1.f + sig) * 0.125f;   // folded (1+mech)/sqrt(dh)
  }
}

// V transpose: qkv v-part [token][d] -> vT[(b*16+h)*64+d][token]
__global__ __launch_bounds__(256) void k_vt(const u16* __restrict__ qkv, u16* __restrict__ vT){
  __shared__ u16 lt[64 * 64];
  const int tid = threadIdx.x;
  const int b = blockIdx.z, h = blockIdx.y, t0 = blockIdx.x * 64;
  const size_t base = (size_t)b * 1024;
#pragma unroll
  for (int i = 0; i < 2; ++i){
    int c = i * 256 + tid;
    int r = c >> 3, ch = c & 7;
    uint4 v = *(const uint4*)(qkv + (base + t0 + r) * 3072 + 2048 + h * 64 + ch * 8);
    *(uint4*)((char*)lt + r * 128 + ((ch ^ (r & 7)) << 4)) = v;
  }
  __syncthreads();
  int d = tid >> 2, tt = (tid & 3) * 16;
  u16 o[16];
#pragma unroll
  for (int j = 0; j < 16; ++j){
    int t = tt + j;
    o[j] = *(const u16*)((char*)lt + t * 128 + (((d >> 3) ^ (t & 7)) << 4) + (d & 7) * 2);
  }
  u16* dst = vT + ((size_t)(b * 16 + h) * 64 + d) * 1024 + t0 + tt;
  *(uint4*)dst = *(uint4*)&o[0];
  *(uint4*)(dst + 8) = *(uint4*)&o[8];
}

// ---------------------------------------------------------------- GEMM
// out[m][n] = act(A[m][:] . W[n][:] + bias[n]) (+resid)
// Depth-2 pipelined staging: 3 LDS buffers (48KB, ~3 blocks/CU), counted vmcnt
// (never 0 in loop), raw s_barrier. BM=128 fixed (BM=256 tried R9: occupancy
// collapse 21%->11%, 74->107us — reverted).
// Block mapping: bijective XCD swizzle -> supertile strips of 8 n-blocks,
// m-major within strip => per-XCD L2 working set ~= A-rows + 8 W-cols (<~4MB).
// (R9 measured: FFN1 FETCH 70MB -> 33MB.)
template<bool GELU_, bool RES, bool OUTF_EN, bool OUTB_EN, bool PARTIAL>
__global__ __launch_bounds__(256) void k_gemm(const u16* __restrict__ A, const u16* __restrict__ W,
                      const float* __restrict__ bias, const float* resid,
                      float* outF, u16* outB, u16* pOut, int M, int N, int K, int nbx){
  __shared__ u16 lA[3][128 * 32];
  __shared__ u16 lB[3][128 * 32];
  const int tid = threadIdx.x;
  const int w = tid >> 6, lane = tid & 63;
  const int lr = lane & 15, lg = lane >> 4;
  // bijective XCD swizzle (m204): each XCD gets a contiguous swz range
  const int nwg = gridDim.x;
  const int q = nwg >> 3, r = nwg & 7;
  const int xcd = blockIdx.x & 7, loc = blockIdx.x >> 3;
  const int swz = (xcd < r ? xcd * (q + 1) : r * (q + 1) + (xcd - r) * q) + loc;
  // supertile: strips of SW n-blocks, m-major within strip
  const int nby = nwg / nbx;
  const int SW = (nbx & 7) ? nbx : 8;
  const int ss = nby * SW;
  const int strip = swz / ss, rem = swz % ss;
  const int m0 = (rem / SW) * 128;
  const int n0 = (strip * SW + rem % SW) * 128;
  const int wr = (w >> 1) * 64, wc = (w & 1) * 64;
  const int kb = blockIdx.z;
  const int Ks = K / gridDim.z;
  const int kbeg = kb * Ks;
  const int nsteps = Ks >> 5;

  f32x4 acc[4][4] = {};
  const char* gA = (const char*)A;
  const char* gW = (const char*)W;

  auto stage = [&](int buf, int k0){
#pragma unroll
    for (int i = 0; i < 2; ++i){
      int c = i * 256 + tid;                 // 16B chunk id (4 chunks/row)
      gld16(gA + (((size_t)(m0 + (c >> 2)) * K + k0) * 2 + (c & 3) * 16),
            (char*)lA + buf * 8192 + i * 4096 + w * 1024);
      gld16(gW + (((size_t)(n0 + (c >> 2)) * K + k0) * 2 + (c & 3) * 16),
            (char*)lB + buf * 8192 + i * 4096 + w * 1024);
    }
  };

  // prologue: stage 2 tiles ahead (8 loads/wave outstanding)
  stage(0, kbeg);
  if (nsteps > 1) stage(1, kbeg + 32);
  int cur = 0, nx = 1, pf = 2;
  for (int s = 0; s < nsteps; ++s){
    if (s + 2 < nsteps) stage(pf, kbeg + (s + 2) * 32);   // 12 outstanding
    // wait ONLY the 4 oldest (tile cur); rest stay in flight across the barrier
    if (s + 2 < nsteps)      asm volatile("s_waitcnt vmcnt(8)" ::: "memory");
    else if (s + 1 < nsteps) asm volatile("s_waitcnt vmcnt(4)" ::: "memory");
    else                     asm volatile("s_waitcnt vmcnt(0)" ::: "memory");
    __builtin_amdgcn_s_barrier();            // tile cur fully in LDS for all waves
    bf16x8 af[4], wf[4];
#pragma unroll
    for (int mb = 0; mb < 4; ++mb)
      af[mb] = *reinterpret_cast<const bf16x8*>(&lA[cur][(wr + mb * 16 + lr) * 32 + lg * 8]);
#pragma unroll
    for (int nb = 0; nb < 4; ++nb)
      wf[nb] = *reinterpret_cast<const bf16x8*>(&lB[cur][(wc + nb * 16 + lr) * 32 + lg * 8]);
#pragma unroll
    for (int mb = 0; mb < 4; ++mb)
#pragma unroll
      for (int nb = 0; nb < 4; ++nb)
        acc[mb][nb] = __builtin_amdgcn_mfma_f32_16x16x32_bf16(af[mb], wf[nb], acc[mb][nb], 0, 0, 0);
    __builtin_amdgcn_s_barrier();            // all waves done reading cur
    int t = cur; cur = nx; nx = pf; pf = t;
  }

#pragma unroll
  for (int mb = 0; mb < 4; ++mb){
#pragma unroll
    for (int nb = 0; nb < 4; ++nb){
      int col = n0 + wc + nb * 16 + lr;
      float bv = PARTIAL ? 0.f : bias[col];
#pragma unroll
      for (int ii = 0; ii < 4; ++ii){
        int row = m0 + wr + mb * 16 + lg * 4 + ii;
        float v = acc[mb][nb][ii] + bv;
        if (GELU_) v = gelu_exact(v);
        size_t idx = (size_t)row * N + col;
        if (RES) v += resid[idx];
        if (PARTIAL) pOut[(size_t)kb * M * N + idx] = f2b(v);
        if (OUTF_EN) outF[idx] = v;
        if (OUTB_EN) outB[idx] = f2b(v);
      }
    }
  }
}

// reduce 2 bf16 K-split partials + bias + resid -> float out
__global__ __launch_bounds__(256) void k_red(const u16* __restrict__ pw, const float* __restrict__ bias,
                     const float* __restrict__ resid, float* __restrict__ outF, int MN, int N){
  int i = (blockIdx.x * 256 + threadIdx.x) * 8;
  uint4 v0 = *(const uint4*)(pw + i);
  uint4 v1 = *(const uint4*)(pw + MN + i);
  const u16* a = (const u16*)&v0;
  const u16* b = (const u16*)&v1;
  int col = i & (N - 1);
  float4 bv0 = *(const float4*)(bias + col);
  float4 bv1 = *(const float4*)(bias + col + 4);
  float4 r0 = *(const float4*)(resid + i);
  float4 r1 = *(const float4*)(resid + i + 4);
  float4 o0, o1;
  o0.x = b2f(a[0]) + b2f(b[0]) + bv0.x + r0.x;
  o0.y = b2f(a[1]) + b2f(b[1]) + bv0.y + r0.y;
  o0.z = b2f(a[2]) + b2f(b[2]) + bv0.z + r0.z;
  o0.w = b2f(a[3]) + b2f(b[3]) + bv0.w + r0.w;
  o1.x = b2f(a[4]) + b2f(b[4]) + bv1.x + r1.x;
  o1.y = b2f(a[5]) + b2f(b[5]) + bv1.y + r1.y;
  o1.z = b2f(a[6]) + b2f(b[6]) + bv1.z + r1.z;
  o1.w = b2f(a[7]) + b2f(b[7]) + bv1.w + r1.w;
  *(float4*)(outF + i) = o0;
  *(float4*)(outF + i + 4) = o1;
}

// ---------------------------------------------------------------- flash attention
// qkv: [B*T][3072] bf16 (q|k|.), vT: [(b*16+h)*64+d][1024] bf16, mechf: (1+mech)/8
__global__ __launch_bounds__(256) void k_attn(const u16* __restrict__ qkv, const u16* __restrict__ vT,
                      const float* __restrict__ mechf, u16* __restrict__ ctx){
  __shared__ u16 lk[64 * 64];        // K tile [key][d], XOR-swizzled chunks
  __shared__ u16 lvt[64 * 64];       // V^T tile [d][key], XOR-swizzled chunks
  __shared__ u16 lpt[4][64 * 16];    // per-wave P^T tile [key][q]
  __shared__ float lmf[64];
  const int tid = threadIdx.x, w = tid >> 6, lane = tid & 63;
  const int lr = lane & 15, lg = lane >> 4;
  const int b = blockIdx.z, h = blockIdx.y, q0 = blockIdx.x * 64;
  const size_t base = (size_t)b * 1024;
  const size_t bh = (size_t)(b * 16 + h);

  bf16x8 qf[2];
  {
    const u16* qrow = qkv + (base + q0 + w * 16 + lr) * 3072 + h * 64;
    qf[0] = *(const bf16x8*)(qrow + lg * 8);
    qf[1] = *(const bf16x8*)(qrow + 32 + lg * 8);
  }
  float m_i[4], l_i[4];
  f32x4 cacc[4] = {};
#pragma unroll
  for (int i = 0; i < 4; ++i){ m_i[i] = -1e30f; l_i[i] = 0.f; }

  char* lkb = (char*)lk;
  char* lvb = (char*)lvt;
  unsigned lpw = (unsigned)(uintptr_t)(__attribute__((address_space(3))) u16*)&lpt[w][0];
  unsigned ta = lpw + lg * 256 + lr * 8;

  for (int jt = 0; jt < 1024; jt += 64){
    __syncthreads();
#pragma unroll
    for (int i = 0; i < 2; ++i){
      int c = i * 256 + tid;                  // 512 chunks of 16B per tile
      int row = c >> 3, ch = c & 7;
      int chs = ch ^ (row & 7);               // pre-swizzled global source
      gld16(qkv + (base + jt + row) * 3072 + 1024 + h * 64 + chs * 8,
            lkb + i * 4096 + w * 1024);
      gld16(vT + (bh * 64 + row) * 1024 + jt + chs * 8,
            lvb + i * 4096 + w * 1024);
    }
    if (tid < 64) lmf[tid] = mechf[base + jt + tid];
    __syncthreads();

    // ---- QK^T (8 MFMA/wave)
    f32x4 s[4];
    __builtin_amdgcn_s_setprio(1);
#pragma unroll
    for (int kb = 0; kb < 4; ++kb){
      int row = kb * 16 + lr;
      bf16x8 kf0 = *(const bf16x8*)(lkb + row * 128 + ((lg ^ (row & 7)) << 4));
      bf16x8 kf1 = *(const bf16x8*)(lkb + row * 128 + (((4 + lg) ^ (row & 7)) << 4));
      f32x4 z = {};
      z = __builtin_amdgcn_mfma_f32_16x16x32_bf16(qf[0], kf0, z, 0, 0, 0);
      z = __builtin_amdgcn_mfma_f32_16x16x32_bf16(qf[1], kf1, z, 0, 0, 0);
      float f = lmf[row];
      s[kb] = z * f;
    }
    __builtin_amdgcn_s_setprio(0);

    // ---- online softmax
    float tm[4];
#pragma unroll
    for (int i = 0; i < 4; ++i)
      tm[i] = fmaxf(fmaxf(s[0][i], s[1][i]), fmaxf(s[2][i], s[3][i]));
#pragma unroll
    for (int off = 1; off < 16; off <<= 1)
#pragma unroll
      for (int i = 0; i < 4; ++i) tm[i] = fmaxf(tm[i], __shfl_xor(tm[i], off, 64));
    float sc[4];
#pragma unroll
    for (int i = 0; i < 4; ++i){
      float mn = fmaxf(m_i[i], tm[i]);
      sc[i] = __expf(m_i[i] - mn);
      m_i[i] = mn;
    }
    // P = exp(s - m); write P^T [key][q] as one b64 per (lane,kb)
#pragma unroll
    for (int kb = 0; kb < 4; ++kb){
      ushort4 pk;
      float p0 = __expf(s[kb][0] - m_i[0]); s[kb][0] = p0; pk.x = f2b(p0);
      float p1 = __expf(s[kb][1] - m_i[1]); s[kb][1] = p1; pk.y = f2b(p1);
      float p2 = __expf(s[kb][2] - m_i[2]); s[kb][2] = p2; pk.z = f2b(p2);
      float p3 = __expf(s[kb][3] - m_i[3]); s[kb][3] = p3; pk.w = f2b(p3);
      *(uint2*)((char*)&lpt[w][0] + (kb * 16 + lr) * 32 + lg * 8) =
          __builtin_bit_cast(uint2, pk);
    }
#pragma unroll
    for (int i = 0; i < 4; ++i){
      float r = (s[0][i] + s[1][i]) + (s[2][i] + s[3][i]);
#pragma unroll
      for (int off = 1; off < 16; off <<= 1) r += __shfl_xor(r, off, 64);
      l_i[i] = l_i[i] * sc[i] + r;
#pragma unroll
      for (int db = 0; db < 4; ++db) cacc[db][i] *= sc[i];
    }

    // ---- P^T -> A-fragments via hardware transpose read
    asm volatile("s_waitcnt lgkmcnt(0)" ::: "memory");
    bf16x4 t00, t01, t10, t11;
    asm volatile("ds_read_b64_tr_b16 %0, %1 offset:0"    : "=v"(t00) : "v"(ta));
    asm volatile("ds_read_b64_tr_b16 %0, %1 offset:128"  : "=v"(t01) : "v"(ta));
    asm volatile("ds_read_b64_tr_b16 %0, %1 offset:1024" : "=v"(t10) : "v"(ta));
    asm volatile("ds_read_b64_tr_b16 %0, %1 offset:1152" : "=v"(t11) : "v"(ta));
    asm volatile("s_waitcnt lgkmcnt(0)");
    __builtin_amdgcn_sched_barrier(0);
    bf16x8 pf0 = __builtin_shufflevector(t00, t01, 0, 1, 2, 3, 4, 5, 6, 7);
    bf16x8 pf1 = __builtin_shufflevector(t10, t11, 0, 1, 2, 3, 4, 5, 6, 7);

    // ---- PV (8 MFMA/wave)
    __builtin_amdgcn_s_setprio(1);
#pragma unroll
    for (int db = 0; db < 4; ++db){
      int row = db * 16 + lr;
      bf16x8 vf0 = *(const bf16x8*)(lvb + row * 128 + ((lg ^ (row & 7)) << 4));
      bf16x8 vf1 = *(const bf16x8*)(lvb + row * 128 + (((4 + lg) ^ (row & 7)) << 4));
      cacc[db] = __builtin_amdgcn_mfma_f32_16x16x32_bf16(pf0, vf0, cacc[db], 0, 0, 0);
      cacc[db] = __builtin_amdgcn_mfma_f32_16x16x32_bf16(pf1, vf1, cacc[db], 0, 0, 0);
    }
    __builtin_amdgcn_s_setprio(0);
  }
  size_t orow0 = base + q0 + w * 16;
#pragma unroll
  for (int db = 0; db < 4; ++db)
#pragma unroll
    for (int i = 0; i < 4; ++i)
      ctx[(orow0 + lg * 4 + i) * 1024 + h * 64 + db * 16 + lr] = f2b(cacc[db][i] / l_i[i]);
}

// ---------------------------------------------------------------- host
extern "C" void kernel_launch(void* const* d_in, const int* in_sizes, int n_in,
                              void* d_out, int out_size, void* d_ws, size_t ws_size,
                              hipStream_t stream){
  const float* x_in = (const float*)d_in[0];
  const float* pos  = (const float*)d_in[1];
  const float* tim  = (const float*)d_in[2];
  const float* Wint = (const float*)d_in[3];
  const float* bint = (const float*)d_in[4];
  const float* g1   = (const float*)d_in[5];
  const float* be1  = (const float*)d_in[6];
  const float* Wq   = (const float*)d_in[7];
  const float* bq   = (const float*)d_in[8];
  const float* Wk   = (const float*)d_in[9];
  const float* bk   = (const float*)d_in[10];
  const float* Wv   = (const float*)d_in[11];
  const float* bv   = (const float*)d_in[12];
  const float* Wo   = (const float*)d_in[13];
  const float* bo   = (const float*)d_in[14];
  const float* Wm1  = (const float*)d_in[15];
  const float* bm1  = (const float*)d_in[16];
  const float* Wm2  = (const float*)d_in[17];
  const float* bm2  = (const float*)d_in[18];
  const float* g2   = (const float*)d_in[19];
  const float* be2  = (const float*)d_in[20];
  const float* W5   = (const float*)d_in[21];
  const float* b5   = (const float*)d_in[22];
  const float* ew   = (const float*)d_in[23];
  const float* g3   = (const float*)d_in[24];
  const float* be3  = (const float*)d_in[25];
  const float* Wf1  = (const float*)d_in[26];
  const float* bf1  = (const float*)d_in[27];
  const float* Wf2  = (const float*)d_in[28];
  const float* bf2  = (const float*)d_in[29];

  float* outX = (float*)d_out;
  float* outM = outX + 4194304;
  float* outW = outX + 4198400;

  char* p = (char*)d_ws;
  auto alloc = [&](size_t bytes) -> char* {
    char* r = p; p += (bytes + 255) & ~(size_t)255; return r;
  };
  u16* Wint_b = (u16*)alloc(1048576 * 2);
  u16* Wqkv_b = (u16*)alloc(3145728 * 2);
  u16* Wm1_b  = (u16*)alloc(524288 * 2);
  u16* Wo_b   = (u16*)alloc(1048576 * 2);
  u16* Wc_b   = (u16*)alloc(1048576 * 2);
  u16* Wf1_b  = (u16*)alloc(4194304 * 2);
  u16* Wf2_b  = (u16*)alloc(4194304 * 2);
  u16* fus_b  = (u16*)alloc(1048576 * 2);
  float* bqkv = (float*)alloc(3072 * 4);
  float* b5c  = (float*)alloc(1024 * 4);
  float* mechf= (float*)alloc(4096 * 4);
  float* tmpF = (float*)alloc(1048576 * 4);
  float* xbuf = (float*)alloc(4194304 * 4);
  u16* h_b    = (u16*)alloc(4194304 * 2);
  char* big   = alloc(36 * 1024 * 1024);        // overlapped region
  u16* qkv_b  = (u16*)big;                      // [4096][3072] bf16 (24MB)
  u16* m1_b   = (u16*)(big + 24 * 1024 * 1024); // [4096][512]  bf16 (4MB)
  u16* ctx_b  = (u16*)(big + 28 * 1024 * 1024); // [4096][1024] bf16 (8MB)
  u16* f1_b   = (u16*)big;                      // [4096][4096] bf16 (32MB) after attn
  u16* vT_b   = h_b;                            // reuse h_b (free after k_mech, until norm2)
  u16* pw_b   = (u16*)d_ws;                     // 16MB FFN2 partials: overlaps Wint..Wf1 (dead by FFN2)

  dim3 blk(256);
  // weight prep: single fused conversion kernel (8 matrices, 13.5M elems)
  ConvArgs ca;
  ca.s[0] = Wint; ca.d[0] = Wint_b;
  ca.s[1] = Wq;   ca.d[1] = Wqkv_b;
  ca.s[2] = Wk;   ca.d[2] = Wqkv_b + 1048576;
  ca.s[3] = Wv;   ca.d[3] = Wqkv_b + 2097152;
  ca.s[4] = Wm1;  ca.d[4] = Wm1_b;
  ca.s[5] = Wo;   ca.d[5] = Wo_b;
  ca.s[6] = Wf1;  ca.d[6] = Wf1_b;
  ca.s[7] = Wf2;  ca.d[7] = Wf2_b;
  ca.cum[0] = 262144;  ca.cum[1] = 524288;  ca.cum[2] = 786432;  ca.cum[3] = 1048576;
  ca.cum[4] = 1179648; ca.cum[5] = 1441792; ca.cum[6] = 2490368; ca.cum[7] = 3538944;
  k_convall<<<13824, blk, 0, stream>>>(ca);
  k_w5<<<4096, blk, 0, stream>>>(W5, b5, ew, Wc_b, b5c, outW);
  k_fused<<<4096, blk, 0, stream>>>(pos, tim, fus_b);
  k_bqkv<<<12, blk, 0, stream>>>(bq, bk, bv, bqkv);

  // fused pos/time GEMM -> tmp, then x = x_in + tmp
  k_gemm<false,false,true,false,false><<<dim3(64, 1, 1), blk, 0, stream>>>(
      fus_b, Wint_b, bint, nullptr, tmpF, nullptr, nullptr, 1024, 1024, 1024, 8);
  k_xinit<<<4096, blk, 0, stream>>>(x_in, tmpF, xbuf);

  // attention block
  k_ln<<<4096, blk, 0, stream>>>(xbuf, g1, be1, h_b);
  k_gemm<false,false,false,true,false><<<dim3(768, 1, 1), blk, 0, stream>>>(
      h_b, Wqkv_b, bqkv, nullptr, nullptr, qkv_b, nullptr, 4096, 3072, 1024, 24);
  k_gemm<true,false,false,true,false><<<dim3(128, 1, 1), blk, 0, stream>>>(
      h_b, Wm1_b, bm1, nullptr, nullptr, m1_b, nullptr, 4096, 512, 1024, 4);
  k_mech<<<1024, blk, 0, stream>>>(m1_b, Wm2, bm2, outM, mechf);
  k_vt<<<dim3(16, 16, 4), blk, 0, stream>>>(qkv_b, vT_b);
  k_attn<<<dim3(16, 16, 4), blk, 0, stream>>>(qkv_b, vT_b, mechf, ctx_b);
  k_gemm<false,true,true,false,false><<<dim3(256, 1, 1), blk, 0, stream>>>(
      ctx_b, Wo_b, bo, xbuf, xbuf, nullptr, nullptr, 4096, 1024, 1024, 8);

  // five-elements layer (W5 pre-reduced)
  k_ln<<<4096, blk, 0, stream>>>(xbuf, g2, be2, h_b);
  k_gemm<false,true,true,false,false><<<dim3(256, 1, 1), blk, 0, stream>>>(
      h_b, Wc_b, b5c, xbuf, xbuf, nullptr, nullptr, 4096, 1024, 1024, 8);

  // FFN
  k_ln<<<4096, blk, 0, stream>>>(xbuf, g3, be3, h_b);
  // FFN1: BM=128 (grid 1024 = 4 blocks/CU) + supertile mapping
  k_gemm<true,false,false,true,false><<<dim3(1024, 1, 1), blk, 0, stream>>>(
      h_b, Wf1_b, bf1, nullptr, nullptr, f1_b, nullptr, 4096, 4096, 1024, 32);
  // FFN2: split-K x2, bf16 partials, then fused reduce(+bias+resid)->outX
  k_gemm<false,false,false,false,true><<<dim3(256, 1, 2), blk, 0, stream>>>(
      f1_b, Wf2_b, nullptr, nullptr, nullptr, nullptr, pw_b, 4096, 1024, 4096, 8);
  k_red<<<2048, blk, 0, stream>>>(pw_b, bf2, xbuf, outX, 4194304, 1024);
}